// Round 18
// baseline (223.404 us; speedup 1.0000x reference)
//
#include <hip/hip_runtime.h>

#define M_TOK 8192
#define N_OUT 4096
#define K_IN  4096

#define AS1 __attribute__((address_space(1)))
#define AS3 __attribute__((address_space(3)))

typedef __attribute__((ext_vector_type(4))) int i32x4;
typedef __attribute__((ext_vector_type(16))) int i32x16;

// inline-asm ds_read_b128: invisible to compiler AA; ordering is OURS via
// counted lgkmcnt + sched_barrier(0) (rule 18).
template <int OFF>
__device__ __forceinline__ i32x4 dsri(unsigned addr) {
    i32x4 r;
    asm volatile("ds_read_b128 %0, %1 offset:%2" : "=v"(r) : "v"(addr), "n"(OFF));
    return r;
}

// ---------------- prepass 1: per-token absmax quant of x (row-major out) ----

__global__ __launch_bounds__(256) void quant_x_kernel(
    const float* __restrict__ x, signed char* __restrict__ xq,
    float* __restrict__ tok_scale)
{
    const int row = blockIdx.x;
    const float4* xr = reinterpret_cast<const float4*>(x + (size_t)row * K_IN);
    const int t = threadIdx.x;
    float4 v[4];
    float m = 0.f;
#pragma unroll
    for (int i = 0; i < 4; ++i) {
        v[i] = xr[t + 256 * i];
        m = fmaxf(m, fmaxf(fmaxf(fabsf(v[i].x), fabsf(v[i].y)),
                           fmaxf(fabsf(v[i].z), fabsf(v[i].w))));
    }
#pragma unroll
    for (int off = 32; off >= 1; off >>= 1)
        m = fmaxf(m, __shfl_xor(m, off, 64));
    __shared__ float wmax[4];
    if ((t & 63) == 0) wmax[t >> 6] = m;
    __syncthreads();
    m = fmaxf(fmaxf(wmax[0], wmax[1]), fmaxf(wmax[2], wmax[3]));
    if (t == 0) tok_scale[row] = m * (1.0f / 127.0f);
    const float inv = (m > 0.f) ? (127.0f / m) : 0.f;
    int* xqi = reinterpret_cast<int*>(xq + (size_t)row * K_IN);
#pragma unroll
    for (int i = 0; i < 4; ++i) {
        const int q0 = __float2int_rn(v[i].x * inv) & 255;
        const int q1 = __float2int_rn(v[i].y * inv) & 255;
        const int q2 = __float2int_rn(v[i].z * inv) & 255;
        const int q3 = __float2int_rn(v[i].w * inv) & 255;
        xqi[t + 256 * i] = q0 | (q1 << 8) | (q2 << 16) | (q3 << 24);
    }
}

// ---------------- prepass 1b: retile xq8 row-major -> frag-tiled -------------

__global__ __launch_bounds__(256) void retile_x_kernel(
    const signed char* __restrict__ xq8, signed char* __restrict__ xqF)
{
    __shared__ __align__(16) char lds[32768];
    const int t = threadIdx.x;
    const int rb = blockIdx.x >> 2;
    const int kc = blockIdx.x & 3;

    const size_t srcBase = (size_t)rb * 32 * K_IN + (size_t)kc * 1024;
#pragma unroll
    for (int j = 0; j < 8; ++j) {
        const int u = j * 256 + t;
        const int row = u >> 6, gc = u & 63;
        const i32x4 v = *reinterpret_cast<const i32x4*>(
            xq8 + srcBase + (size_t)row * K_IN + gc * 16);
        *reinterpret_cast<i32x4*>(
            lds + ((row * 64 + (gc ^ (row & 7))) * 16)) = v;
    }
    __syncthreads();

    const int l = t & 63;
    const int W = t >> 6;
    const int row = l & 31;
    const int hi = l >> 5;
    i32x4* dst0 = reinterpret_cast<i32x4*>(xqF) +
                  ((size_t)rb * 128 + kc * 32) * 64 + l;
#pragma unroll
    for (int i = 0; i < 8; ++i) {
        const int kfl = W * 8 + i;
        const int gc = (kfl * 2 + hi) ^ (row & 7);
        const i32x4 v = *reinterpret_cast<const i32x4*>(
            lds + ((row * 64 + gc) * 16));
        dst0[(size_t)kfl * 64] = v;
    }
}

// ---------------- prepass 2: pack Wq int32 -> int8, frag-tiled ---------------

__global__ __launch_bounds__(256) void pack_w_frag_kernel(
    const int* __restrict__ wq, signed char* __restrict__ wqF)
{
    const int t = threadIdx.x;
    const int l = t & 63;
    const int W = t >> 6;
    const int rb = blockIdx.x >> 3;
    const int pc = blockIdx.x & 7;
    const int r = rb * 32 + (l & 31);
    const int4* wr4 = reinterpret_cast<const int4*>(wq) + (size_t)r * 1024;
    i32x4* outF = reinterpret_cast<i32x4*>(wqF) + (size_t)rb * 128 * 64 + l;
#pragma unroll
    for (int q = 0; q < 4; ++q) {
        const int f = W + 4 * (pc * 4 + q);
        const int c4 = f * 8 + (l >> 5) * 4;
        i32x4 o;
#pragma unroll
        for (int j = 0; j < 4; ++j) {
            const int4 a = wr4[c4 + j];
            o[j] = (a.x & 255) | ((a.y & 255) << 8) | ((a.z & 255) << 16) | ((a.w & 255) << 24);
        }
        outF[(size_t)f * 64] = o;
    }
}

// ------- int8 GEMM R18: 4 WAVES/SIMD (acc[2][2]), 128x128 tile, 4 blocks/CU --
// R10-R17: body = 2.12 x MFMA-work at EVERY structure tried; the single
// invariant was 2 waves/SIMD (VGPR-capped). uBench peaks were measured at 8
// waves/SIMD. Hypothesis: MFMA sustained rate scales with waves/SIMD below
// saturation. Test: shrink wave output to 64x64 (acc[2][2] = 64 regs; total
// ~115 -> 128-reg quantum) -> 4 waves/SIMD, 16 waves/CU, 4 blocks/CU (4
// independent barrier domains).
// Block: 256 thr = 4 waves (wr=w>>1, wc=w&1); tile 128x128, BK=32, ring-4,
// LDS 32KB (A 4x4KB + B 4x4KB). Frag-linear LDS + frag-tiled global.
// Body T: lgkm(0) [tile T's 4 reads, issued last body] -> 4 MFMA; RD4(T+1) +
// stage(T+3) [2 glds]; vmcnt(2) [confirms stage(T+1),(T+2); leaves (T+3)];
// barrier. Prologue vmcnt(2) confirms tiles 0,1. Tail: VM=0 at 125,126.
// WAR: stage(T+3) -> slot (T-1)&3; tile T-1 reads drained by body T-1's
// lgkm(0) + its barrier. Race-audited.

#define NKT 128            // K tiles of 32
#define SLOTA 4096         // 4 A frags x 1KB (128 rows)
#define SLOTB 4096         // 4 B frags x 1KB (128 rows)

#define MFMA(a, b, c) c = __builtin_amdgcn_mfma_i32_32x32x32_i8(a, b, c, 0, 0, 0)

// 4 reads: A0,A1 (mb 0,1), B0,B1 (nb 0,1)
#define RD4(P, aA, bA)                          \
    P##_A0 = dsri<0>(aA);                       \
    P##_A1 = dsri<1024>(aA);                    \
    P##_B0 = dsri<0>(bA);                       \
    P##_B1 = dsri<1024>(bA);

#define CL4(P)                                                \
    MFMA(P##_A0, P##_B0, acc00); MFMA(P##_A0, P##_B1, acc01); \
    MFMA(P##_A1, P##_B0, acc10); MFMA(P##_A1, P##_B1, acc11);

#define GBODY(T, C, N, DO_STAGE, VM)                                      \
    {                                                                     \
        asm volatile("s_waitcnt lgkmcnt(0)" ::: "memory");                \
        __builtin_amdgcn_sched_barrier(0);                                \
        __builtin_amdgcn_s_setprio(1);                                    \
        CL4(C)                                                            \
        __builtin_amdgcn_s_setprio(0);                                    \
        __builtin_amdgcn_sched_barrier(0);                                \
        const unsigned aN_ = aBase + (unsigned)((((T) + 1) & 3) * SLOTA); \
        const unsigned bN_ = bBase + (unsigned)((((T) + 1) & 3) * SLOTB); \
        RD4(N, aN_, bN_)                                                  \
        if (DO_STAGE) stageAB((T) + 3);                                   \
        asm volatile("s_waitcnt vmcnt(" #VM ")" ::: "memory");            \
        __builtin_amdgcn_sched_barrier(0);                                \
        __builtin_amdgcn_s_barrier();                                     \
        __builtin_amdgcn_sched_barrier(0);                                \
    }

#define GFINAL(C)                                                         \
    {                                                                     \
        asm volatile("s_waitcnt lgkmcnt(0)" ::: "memory");                \
        __builtin_amdgcn_sched_barrier(0);                                \
        __builtin_amdgcn_s_setprio(1);                                    \
        CL4(C)                                                            \
        __builtin_amdgcn_s_setprio(0);                                    \
        __builtin_amdgcn_sched_barrier(0);                                \
    }

__global__ __launch_bounds__(256, 4) void qgemm_i8o4_kernel(
    const signed char* __restrict__ xqF,
    const signed char* __restrict__ wqF,
    const float* __restrict__ tok_scale,
    const float* __restrict__ row_scales,
    const float* __restrict__ bias,
    float* __restrict__ out)
{
    __shared__ __align__(16) char smem[32768];  // A [0,16K): 4x4KB; B [16K,32K): 4x4KB

    const int tid = threadIdx.x;
    const int l = tid & 63;
    const int w = tid >> 6;      // 0..3
    const int wr = w >> 1;       // 0..1
    const int wc = w & 1;        // 0..1

    // XCD-aware bijective swizzle (nwg = 2048, 2048 % 8 == 0)
    const int bid = blockIdx.x;
    const int swz = (bid & 7) * 256 + (bid >> 3);
    const int bm = swz >> 5;     // 0..63
    const int bn = swz & 31;     // 0..31

    // ---- staging: wave w stages A frag w and B frag w of each tile ----
    // frag-tiled global: frag (rb, kf) at (rb*128 + kf)*1024 + lane*16.
    const signed char* aS = xqF + ((size_t)(bm * 4 + w) * 128) * 1024 + (size_t)l * 16;
    const signed char* bS = wqF + ((size_t)(bn * 4 + w) * 128) * 1024 + (size_t)l * 16;
    char* aDst = smem + w * 1024;
    char* bDst = smem + 16384 + w * 1024;

    auto stageAB = [&](int tt) {
        __builtin_amdgcn_global_load_lds(
            (const AS1 void*)(aS + (size_t)tt * 1024),
            (AS3 void*)(aDst + (tt & 3) * SLOTA), 16, 0, 0);
        __builtin_amdgcn_global_load_lds(
            (const AS1 void*)(bS + (size_t)tt * 1024),
            (AS3 void*)(bDst + (tt & 3) * SLOTB), 16, 0, 0);
    };

    // ---- fragment-linear ds_read bases ----
    // A: wave wr reads frags wr*2 + mb at (wr*2+mb)*1024 within the slot.
    // B: wave wc reads frags wc*2 + nb at (wc*2+nb)*1024 within the slot.
    const unsigned sbase = (unsigned)(uintptr_t)(AS3 char*)smem;
    const unsigned aBase = sbase + (unsigned)(wr * 2048 + l * 16);            // + slot*4KB + mb*1024
    const unsigned bBase = sbase + 16384u + (unsigned)(wc * 2048 + l * 16);   // + slot*4KB + nb*1024

    i32x16 acc00 = {0}, acc01 = {0}, acc10 = {0}, acc11 = {0};

    i32x4 X_A0, X_A1, X_B0, X_B1;
    i32x4 Y_A0, Y_A1, Y_B0, Y_B1;

    // ---- prologue: stage tiles 0,1,2 (6 glds); vmcnt(2) confirms tiles 0,1 ----
    stageAB(0); stageAB(1); stageAB(2);
    asm volatile("s_waitcnt vmcnt(2)" ::: "memory");
    __builtin_amdgcn_sched_barrier(0);
    __builtin_amdgcn_s_barrier();
    __builtin_amdgcn_sched_barrier(0);
    RD4(X, aBase, bBase)

    // ---- main loop: bodies 0..124 (VM=2), 125..126 (VM=0), 127 = final ----
    for (int t = 0; t < 124; t += 2) {
        GBODY(t,     X, Y, true, 2);
        GBODY(t + 1, Y, X, true, 2);
    }
    GBODY(124, X, Y, true, 2);    // stages tile 127 (the last)
    GBODY(125, Y, X, false, 0);
    GBODY(126, X, Y, false, 0);
    GFINAL(Y)

    // ---- epilogue: dequant (tok_scale via global, L2-hot), store ----
    const int cl = l & 31;
    const int rg4 = (l >> 5) * 4;
    const int gcol0 = bn * 128 + wc * 64;
    const float* tsrow = tok_scale + bm * 128 + wr * 64;
    float cs[2], bb[2];
#pragma unroll
    for (int nb = 0; nb < 2; ++nb) {
        const int col = gcol0 + nb * 32 + cl;
        cs[nb] = row_scales[col] * (1.0f / 127.0f);
        bb[nb] = bias[col];
    }
    const i32x16* accs[2][2] = {{&acc00, &acc01}, {&acc10, &acc11}};
#pragma unroll
    for (int mb = 0; mb < 2; ++mb) {
#pragma unroll
        for (int reg = 0; reg < 16; ++reg) {
            const int rl = mb * 32 + (reg & 3) + 8 * (reg >> 2) + rg4;
            const float tsv = tsrow[rl];
            float* orow = out + (size_t)(bm * 128 + wr * 64 + rl) * N_OUT + gcol0 + cl;
#pragma unroll
            for (int nb = 0; nb < 2; ++nb) {
                const int a = (*accs[mb][nb])[reg];
                orow[nb * 32] = (float)a * tsv * cs[nb] + bb[nb];
            }
        }
    }
}

// ---------------- launch ----------------

extern "C" void kernel_launch(void* const* d_in, const int* in_sizes, int n_in,
                              void* d_out, int out_size, void* d_ws, size_t ws_size,
                              hipStream_t stream) {
    const float* x = (const float*)d_in[0];
    const int* wq = (const int*)d_in[1];
    const float* row_scales = (const float*)d_in[2];
    const float* bias = (const float*)d_in[3];
    float* out = (float*)d_out;

    signed char* xq8 = (signed char*)d_ws;                       // 32 MiB row-major
    signed char* xqF = xq8 + (size_t)M_TOK * K_IN;               // 32 MiB frag-tiled
    signed char* wqF = xqF + (size_t)M_TOK * K_IN;               // 16 MiB frag-tiled
    float* tok_scale = (float*)(wqF + (size_t)N_OUT * K_IN);     // 32 KiB
    (void)ws_size;

    quant_x_kernel<<<M_TOK, 256, 0, stream>>>(x, xq8, tok_scale);
    pack_w_frag_kernel<<<1024, 256, 0, stream>>>(wq, wqF);
    retile_x_kernel<<<1024, 256, 0, stream>>>(xq8, xqF);

    const int nblocks = (M_TOK / 128) * (N_OUT / 128);  // 2048
    qgemm_i8o4_kernel<<<nblocks, 256, 0, stream>>>(
        xqF, wqF, tok_scale, row_scales, bias, out);
}